// Round 1
// baseline (1629.492 us; speedup 1.0000x reference)
//
#include <hip/hip_runtime.h>
#include <hip/hip_bf16.h>

#define OUT_CH 64
#define KSZ 7
#define STRIDE 2
#define PAD 3
#define HIDDEN 128
#define MAX_IN 3
#define B_SZ 32
#define H_IN 224
#define W_IN 224
#define H_OUT 112
#define W_OUT 112
#define WPB (MAX_IN * KSZ * KSZ)          // 147 weights per (b, oc)
#define OUT_DIM (OUT_CH * WPB)            // 9408

// ---------------- Kernel A: h = relu(mask @ W1 + b1) ----------------
// grid(B_SZ), block(HIDDEN)
__global__ void mlp1_kernel(const float* __restrict__ mask,
                            const float* __restrict__ W1,
                            const float* __restrict__ b1,
                            float* __restrict__ h) {
    int b = blockIdx.x;
    int j = threadIdx.x;
    float acc = b1[j];
#pragma unroll
    for (int c = 0; c < MAX_IN; ++c) {
        acc += mask[b * MAX_IN + c] * W1[c * HIDDEN + j];
    }
    h[b * HIDDEN + j] = fmaxf(acc, 0.0f);
}

// ---------------- Kernel B: weights = h @ W2 + b2 ----------------
// grid(ceil(OUT_DIM/256), B_SZ), block(256)
__global__ void mlp2_kernel(const float* __restrict__ h,
                            const float* __restrict__ W2,
                            const float* __restrict__ b2,
                            float* __restrict__ wbuf) {
    __shared__ float hs[HIDDEN];
    int b = blockIdx.y;
    if (threadIdx.x < HIDDEN) hs[threadIdx.x] = h[b * HIDDEN + threadIdx.x];
    __syncthreads();
    int o = blockIdx.x * 256 + threadIdx.x;
    if (o >= OUT_DIM) return;
    float acc = b2[o];
#pragma unroll 8
    for (int j = 0; j < HIDDEN; ++j) {
        acc += hs[j] * W2[j * OUT_DIM + o];
    }
    wbuf[b * OUT_DIM + o] = acc;
}

// ---------------- Kernel C: grouped conv ----------------
// grid(49, B_SZ*OUT_CH), block(256). One thread per output pixel.
__global__ void conv_kernel(const float* __restrict__ x,
                            const float* __restrict__ wbuf,
                            float* __restrict__ out) {
    __shared__ float ws[WPB];
    int by = blockIdx.y;               // b*64 + oc
    int b = by >> 6;
    // stage the 147 weights for this (b, oc)
    if (threadIdx.x < WPB) ws[threadIdx.x] = wbuf[by * WPB + threadIdx.x];
    __syncthreads();

    int p = blockIdx.x * 256 + threadIdx.x;   // 49*256 == 12544 == H_OUT*W_OUT exactly
    int oh = p / W_OUT;
    int ow = p - oh * W_OUT;

    int ih0 = oh * STRIDE - PAD;
    int iw0 = ow * STRIDE - PAD;

    const float* xb = x + (size_t)b * MAX_IN * H_IN * W_IN;

    float acc = 0.0f;
#pragma unroll
    for (int c = 0; c < MAX_IN; ++c) {
        const float* xc = xb + (size_t)c * H_IN * W_IN;
        const float* wc = ws + c * KSZ * KSZ;
#pragma unroll
        for (int kh = 0; kh < KSZ; ++kh) {
            int ih = ih0 + kh;
            if ((unsigned)ih >= (unsigned)H_IN) continue;
            const float* xrow = xc + (size_t)ih * W_IN;
            const float* wrow = wc + kh * KSZ;
#pragma unroll
            for (int kw = 0; kw < KSZ; ++kw) {
                int iw = iw0 + kw;
                if ((unsigned)iw >= (unsigned)W_IN) continue;
                acc = fmaf(xrow[iw], wrow[kw], acc);
            }
        }
    }
    out[(size_t)by * (H_OUT * W_OUT) + p] = acc;
}

extern "C" void kernel_launch(void* const* d_in, const int* in_sizes, int n_in,
                              void* d_out, int out_size, void* d_ws, size_t ws_size,
                              hipStream_t stream) {
    const float* x    = (const float*)d_in[0];   // [32,3,224,224]
    const float* mask = (const float*)d_in[1];   // [32,3]
    const float* W1   = (const float*)d_in[2];   // [3,128]
    const float* b1   = (const float*)d_in[3];   // [128]
    const float* W2   = (const float*)d_in[4];   // [128,9408]
    const float* b2   = (const float*)d_in[5];   // [9408]
    float* out = (float*)d_out;

    // workspace layout
    float* h    = (float*)d_ws;                           // 32*128 floats = 16 KB
    float* wbuf = (float*)((char*)d_ws + 16384);          // 32*9408 floats = 1.20 MB

    mlp1_kernel<<<dim3(B_SZ), dim3(HIDDEN), 0, stream>>>(mask, W1, b1, h);
    mlp2_kernel<<<dim3((OUT_DIM + 255) / 256, B_SZ), dim3(256), 0, stream>>>(h, W2, b2, wbuf);
    conv_kernel<<<dim3(49, B_SZ * OUT_CH), dim3(256), 0, stream>>>(x, wbuf, out);
}

// Round 2
// 149.356 us; speedup vs baseline: 10.9101x; 10.9101x over previous
//
#include <hip/hip_runtime.h>
#include <hip/hip_bf16.h>

#define OUT_CH 64
#define KSZ 7
#define STRIDE 2
#define PAD 3
#define HIDDEN 128
#define MAX_IN 3
#define B_SZ 32
#define H_IN 224
#define W_IN 224
#define H_OUT 112
#define W_OUT 112
#define WPB (MAX_IN * KSZ * KSZ)          // 147 weights per (b, oc)
#define OUT_DIM (OUT_CH * WPB)            // 9408

// conv tiling
#define SLOTS 16                          // pixel slots per row: 16 * 7 = 112
#define PPT 7                             // pixels (output cols) per thread
#define OGRP 4                            // output channels per thread (16 groups * 4 = 64)
#define XROW_LDS 232                      // 229 needed (iw -3..225 -> j 0..228), padded
#define NROWS 21                          // 3 channels * 7 kh rows

// ---------------- Kernel A: h = relu(mask @ W1 + b1) ----------------
__global__ void mlp1_kernel(const float* __restrict__ mask,
                            const float* __restrict__ W1,
                            const float* __restrict__ b1,
                            float* __restrict__ h) {
    int b = blockIdx.x;
    int j = threadIdx.x;
    float acc = b1[j];
#pragma unroll
    for (int c = 0; c < MAX_IN; ++c) {
        acc += mask[b * MAX_IN + c] * W1[c * HIDDEN + j];
    }
    h[b * HIDDEN + j] = fmaxf(acc, 0.0f);
}

// ---------------- Kernel B: weights = h @ W2 + b2, stored TRANSPOSED ----------------
// wbuf[b][tap][oc]  (tap = c*49 + kh*7 + kw, 147 taps; oc 0..63)
__global__ void mlp2_kernel(const float* __restrict__ h,
                            const float* __restrict__ W2,
                            const float* __restrict__ b2,
                            float* __restrict__ wbuf) {
    __shared__ float hs[HIDDEN];
    int b = blockIdx.y;
    if (threadIdx.x < HIDDEN) hs[threadIdx.x] = h[b * HIDDEN + threadIdx.x];
    __syncthreads();
    int o = blockIdx.x * 256 + threadIdx.x;
    if (o >= OUT_DIM) return;
    float acc = b2[o];
#pragma unroll 8
    for (int j = 0; j < HIDDEN; ++j) {
        acc += hs[j] * W2[j * OUT_DIM + o];
    }
    int oc  = o / WPB;
    int tap = o - oc * WPB;
    wbuf[b * OUT_DIM + tap * OUT_CH + oc] = acc;
}

// ---------------- Kernel C: grouped conv, LDS-tiled ----------------
// grid(H_OUT, B_SZ), block(256). Block: one (b, oh), all 112 ow, all 64 oc.
// Thread t: g = t>>4 (oc group, ocs g*4..g*4+3), s = t&15 (cols s*7..s*7+6).
__global__ void __launch_bounds__(256, 1)
conv_kernel(const float* __restrict__ x,
            const float* __restrict__ wbuf,
            float* __restrict__ out) {
    __shared__ float xs[NROWS * XROW_LDS];   // 4872 f = 19.5 KB, j <-> iw = j-3
    __shared__ float wlds[OUT_DIM];          // [tap][64] = 37.6 KB

    const int oh = blockIdx.x;
    const int b  = blockIdx.y;
    const int tid = threadIdx.x;

    // ---- stage weights (coalesced copy; already transposed) ----
    const float* wsrc = wbuf + (size_t)b * OUT_DIM;
    for (int i = tid; i < OUT_DIM; i += 256) wlds[i] = wsrc[i];

    // ---- stage input rows with zero-padded halo ----
    const float* xb = x + (size_t)b * MAX_IN * H_IN * W_IN;
    for (int i = tid; i < NROWS * XROW_LDS; i += 256) {
        int r = i / XROW_LDS;          // 0..20 : c*7 + kh
        int j = i - r * XROW_LDS;      // 0..231
        int c  = r / KSZ;
        int kh = r - c * KSZ;
        int ih = oh * STRIDE + kh - PAD;
        int iw = j - PAD;
        float v = 0.0f;
        if ((unsigned)ih < (unsigned)H_IN && (unsigned)iw < (unsigned)W_IN)
            v = xb[((size_t)c * H_IN + ih) * W_IN + iw];
        xs[i] = v;
    }
    __syncthreads();

    const int g = tid >> 4;            // 0..15
    const int s = tid & 15;            // 0..15
    const int xbase = 14 * s;          // = 2*(s*7) ; j index of iw0+3 for kw=0,p=0

    float acc[OGRP][PPT];
#pragma unroll
    for (int o = 0; o < OGRP; ++o)
#pragma unroll
        for (int p = 0; p < PPT; ++p) acc[o][p] = 0.0f;

    for (int ckh = 0; ckh < NROWS; ++ckh) {
        const float* xr = &xs[ckh * XROW_LDS + xbase];
        float xw[20];
#pragma unroll
        for (int i = 0; i < 10; ++i)
            *(float2*)&xw[2 * i] = *(const float2*)&xr[2 * i];

        const float* wp = &wlds[(ckh * KSZ) * OUT_CH + g * OGRP];
#pragma unroll
        for (int kw = 0; kw < KSZ; ++kw) {
            float4 w4 = *(const float4*)&wp[kw * OUT_CH];
#pragma unroll
            for (int o = 0; o < OGRP; ++o) {
                float wv = ((const float*)&w4)[o];
#pragma unroll
                for (int p = 0; p < PPT; ++p)
                    acc[o][p] = fmaf(xw[2 * p + kw], wv, acc[o][p]);
            }
        }
    }

    // ---- write out: out[b][oc][oh][ow] ----
    const int ow0 = s * PPT;
#pragma unroll
    for (int o = 0; o < OGRP; ++o) {
        int oc = g * OGRP + o;
        float* orow = out + (((size_t)b * OUT_CH + oc) * H_OUT + oh) * W_OUT + ow0;
#pragma unroll
        for (int p = 0; p < PPT; ++p) orow[p] = acc[o][p];
    }
}

extern "C" void kernel_launch(void* const* d_in, const int* in_sizes, int n_in,
                              void* d_out, int out_size, void* d_ws, size_t ws_size,
                              hipStream_t stream) {
    const float* x    = (const float*)d_in[0];   // [32,3,224,224]
    const float* mask = (const float*)d_in[1];   // [32,3]
    const float* W1   = (const float*)d_in[2];   // [3,128]
    const float* b1   = (const float*)d_in[3];   // [128]
    const float* W2   = (const float*)d_in[4];   // [128,9408]
    const float* b2   = (const float*)d_in[5];   // [9408]
    float* out = (float*)d_out;

    float* h    = (float*)d_ws;                           // 32*128 floats = 16 KB
    float* wbuf = (float*)((char*)d_ws + 16384);          // 32*9408 floats = 1.20 MB

    mlp1_kernel<<<dim3(B_SZ), dim3(HIDDEN), 0, stream>>>(mask, W1, b1, h);
    mlp2_kernel<<<dim3((OUT_DIM + 255) / 256, B_SZ), dim3(256), 0, stream>>>(h, W2, b2, wbuf);
    conv_kernel<<<dim3(H_OUT, B_SZ), dim3(256), 0, stream>>>(x, wbuf, out);
}

// Round 3
// 53.509 us; speedup vs baseline: 30.4525x; 2.7912x over previous
//
#include <hip/hip_runtime.h>
#include <hip/hip_bf16.h>

#define OUT_CH 64
#define KSZ 7
#define STRIDE 2
#define PAD 3
#define HIDDEN 128
#define MAX_IN 3
#define B_SZ 32
#define H_IN 224
#define W_IN 224
#define H_OUT 112
#define W_OUT 112
#define WPB 147                       // 3*7*7 taps per (b,oc)
#define OUT_DIM (OUT_CH * WPB)        // 9408
#define SEGS 21                       // 3 channels * 7 kh rows
#define SEGP 24                       // padded segment count (6 MFMAs * 4)
#define WQ_PER_B (OUT_CH * SEGP * 8)  // 12288 bf16 per batch row
#define XRW 120                       // u32 per LDS x-row (240 bf16)

typedef __attribute__((ext_vector_type(8))) short short8;
typedef __attribute__((ext_vector_type(4))) float floatx4;

// ---------------- Kernel A: h = relu(mask @ W1 + b1) ----------------
__global__ void mlp1_kernel(const float* __restrict__ mask,
                            const float* __restrict__ W1,
                            const float* __restrict__ b1,
                            float* __restrict__ h) {
    int b = blockIdx.x;
    int j = threadIdx.x;
    float acc = b1[j];
#pragma unroll
    for (int c = 0; c < MAX_IN; ++c) {
        acc += mask[b * MAX_IN + c] * W1[c * HIDDEN + j];
    }
    h[b * HIDDEN + j] = fmaxf(acc, 0.0f);
}

// ---------------- Kernel B: weights -> padded bf16 A-operand layout ----------------
// wq[b][oc][seg(24)][t(8)] bf16; seg = c*7+kh (<21 real), t = kw (<7 real), pads = 0.
// grid(B_SZ, 48), block(256) — covers all 12288 padded slots per b.
__global__ void mlp2_kernel(const float* __restrict__ h,
                            const float* __restrict__ W2,
                            const float* __restrict__ b2,
                            __hip_bfloat16* __restrict__ wq) {
    __shared__ float hs[HIDDEN];
    int b = blockIdx.x;
    int tid = threadIdx.x;
    if (tid < HIDDEN) hs[tid] = h[b * HIDDEN + tid];
    __syncthreads();
    int op = blockIdx.y * 256 + tid;          // 0..12287
    int oc  = op / (SEGP * 8);
    int rem = op - oc * (SEGP * 8);
    int seg = rem >> 3;
    int t   = rem & 7;
    float acc = 0.0f;
    if (seg < SEGS && t < 7) {
        int c  = seg / KSZ;
        int kh = seg - c * KSZ;
        int o = oc * WPB + c * 49 + kh * 7 + t;
        acc = b2[o];
#pragma unroll 8
        for (int j = 0; j < HIDDEN; ++j) {
            acc += hs[j] * W2[j * OUT_DIM + o];
        }
    }
    wq[(size_t)b * WQ_PER_B + op] = __float2bfloat16(acc);
}

// ---------------- Kernel C: grouped conv as implicit GEMM (MFMA) ----------------
// grid(H_OUT, B_SZ), block(256) = 4 waves. Wave w: oc-tile w (16 ocs).
// Per (b,oh): C[64][112] = W'[64][192] * P[192][112], 6 MFMAs per 16x16 tile.
__global__ void __launch_bounds__(256, 4)
conv_kernel(const float* __restrict__ x,
            const __hip_bfloat16* __restrict__ wq,
            float* __restrict__ out) {
    __shared__ unsigned int xs[SEGS * XRW];   // [seg][240 bf16] as u32 pairs, 10.1 KB

    const int oh  = blockIdx.x;
    const int b   = blockIdx.y;
    const int tid = threadIdx.x;

    // ---- stage x rows: f32 -> bf16, zero-padded halo (iw = u-3) ----
    const float* xb = x + (size_t)b * MAX_IN * H_IN * W_IN;
    for (int i = tid; i < SEGS * XRW; i += 256) {
        int seg = i / XRW;
        int uw  = i - seg * XRW;
        int c   = seg / KSZ;
        int kh  = seg - c * KSZ;
        int ih  = oh * STRIDE + kh - PAD;
        int iw0 = uw * 2 - PAD;
        float f0 = 0.0f, f1 = 0.0f;
        if ((unsigned)ih < (unsigned)H_IN) {
            const float* xr = xb + ((size_t)c * H_IN + ih) * W_IN;
            if ((unsigned)iw0 < (unsigned)W_IN)       f0 = xr[iw0];
            if ((unsigned)(iw0 + 1) < (unsigned)W_IN) f1 = xr[iw0 + 1];
        }
        unsigned int lo = __bfloat16_as_ushort(__float2bfloat16(f0));
        unsigned int hi = __bfloat16_as_ushort(__float2bfloat16(f1));
        xs[i] = lo | (hi << 16);
    }
    __syncthreads();

    const int wv = tid >> 6;            // oc-tile 0..3
    const int l  = tid & 63;
    const int lr = l & 15;              // A row / B col / D col
    const int lg = l >> 4;              // k-group / D row group

    // ---- A-fragments: one 16B load per MFMA, straight from global wq ----
    const unsigned short* wb = (const unsigned short*)wq
        + ((size_t)b * OUT_CH + wv * 16 + lr) * (SEGP * 8);
    short8 afr[6];
#pragma unroll
    for (int mi = 0; mi < 6; ++mi)
        afr[mi] = *(const short8*)(wb + (4 * mi + lg) * 8);  // 16B aligned

    // ---- 7 pixel tiles of 16 ----
#pragma unroll
    for (int t = 0; t < 7; ++t) {
        const int ow = t * 16 + lr;
        floatx4 acc = {0.0f, 0.0f, 0.0f, 0.0f};
#pragma unroll
        for (int mi = 0; mi < 6; ++mi) {
            int seg = 4 * mi + lg;
            if (seg >= SEGS) seg = 0;          // weights are 0 there; any finite row ok
            const unsigned int* xr = xs + seg * XRW + ow;
            union { short8 s; unsigned int u[4]; } bu;
            bu.u[0] = xr[0];
            bu.u[1] = xr[1];
            bu.u[2] = xr[2];
            bu.u[3] = xr[3];
            acc = __builtin_amdgcn_mfma_f32_16x16x32_bf16(afr[mi], bu.s, acc, 0, 0, 0);
        }
        float* op = out + (((size_t)b * OUT_CH + wv * 16 + lg * 4) * H_OUT + oh) * W_OUT + ow;
#pragma unroll
        for (int r = 0; r < 4; ++r)
            op[(size_t)r * H_OUT * W_OUT] = acc[r];
    }
}

extern "C" void kernel_launch(void* const* d_in, const int* in_sizes, int n_in,
                              void* d_out, int out_size, void* d_ws, size_t ws_size,
                              hipStream_t stream) {
    const float* x    = (const float*)d_in[0];   // [32,3,224,224]
    const float* mask = (const float*)d_in[1];   // [32,3]
    const float* W1   = (const float*)d_in[2];   // [3,128]
    const float* b1   = (const float*)d_in[3];   // [128]
    const float* W2   = (const float*)d_in[4];   // [128,9408]
    const float* b2   = (const float*)d_in[5];   // [9408]
    float* out = (float*)d_out;

    float* h = (float*)d_ws;                                   // 16 KB
    __hip_bfloat16* wq = (__hip_bfloat16*)((char*)d_ws + 16384); // 32*12288*2 = 768 KB

    mlp1_kernel<<<dim3(B_SZ), dim3(HIDDEN), 0, stream>>>(mask, W1, b1, h);
    mlp2_kernel<<<dim3(B_SZ, 48), dim3(256), 0, stream>>>(h, W2, b2, wq);
    conv_kernel<<<dim3(H_OUT, B_SZ), dim3(256), 0, stream>>>(x, wq, out);
}